// Round 4
// baseline (1880.396 us; speedup 1.0000x reference)
//
#include <hip/hip_runtime.h>
#include <hip/hip_bf16.h>
#include <float.h>

// OneHopRanker on MI355X — round 6: LDS-free score_mfma.
// Round-5 counters for score_mfma: MfmaUtil 8%, VALUBusy 15%, HBM 13.5%,
// occupancy 31%, 2M LDS bank-conflict cycles -> latency-bound serial pipeline
// (load->drain->pack->LDS->barrier->compute). This version loads B fragments
// directly global->VGPR (fp32) and truncates to bf16 in-register with the
// identical >>16 packing -> bit-identical tilemax, no barrier, no LDS, no
// staging VALU; compiler free to pipeline loads against MFMA.
// All other kernels byte-identical to round 5 (attribution).

#define TILE 64        // candidates per max-tile
#define KSEL 32        // final top-k
#define TSEL 64        // tiles selected per query for exact rescore
#define CB   128       // candidates per score block (2 tiles)
#define NT_MAX 7936    // >= ceil(500000/64)=7813
#define EQCAP 256      // tie-list capacity (radix boundary ties)
#define POOLCAP 256    // final top-k pool capacity

typedef __attribute__((ext_vector_type(8))) short s16x8;   // 8 bf16 (4 VGPRs)
typedef __attribute__((ext_vector_type(4))) float f32x4;

// float -> order-preserving unsigned key (larger float => larger key)
__device__ __forceinline__ unsigned f2key(float f) {
  unsigned u = __float_as_uint(f);
  return (u & 0x80000000u) ? ~u : (u | 0x80000000u);
}

// two float4 (8 consecutive fp32) -> 8 bf16 by truncation, elem order kept.
// Identical bit-pattern to the round-5 LDS staging pack.
__device__ __forceinline__ s16x8 pack_bf16(float4 a, float4 b) {
  union { s16x8 v; unsigned u[4]; } r;
  r.u[0] = (__float_as_uint(a.y) & 0xffff0000u) | (__float_as_uint(a.x) >> 16);
  r.u[1] = (__float_as_uint(a.w) & 0xffff0000u) | (__float_as_uint(a.z) >> 16);
  r.u[2] = (__float_as_uint(b.y) & 0xffff0000u) | (__float_as_uint(b.x) >> 16);
  r.u[3] = (__float_as_uint(b.w) & 0xffff0000u) | (__float_as_uint(b.z) >> 16);
  return r.v;
}

// ---------------- fp32 -> bf16 (truncation) query conversion ----------------
__global__ void cvt_a_kernel(const float* __restrict__ A,
                             unsigned short* __restrict__ Abf, int nelem) {
  int i = blockIdx.x * 256 + threadIdx.x;
  if (i < nelem) Abf[i] = (unsigned short)(__float_as_uint(A[i]) >> 16);
}

// ---------------- stage 1: fused bf16 GEMM + per-tile max (LDS-FREE) --------
// Block: 256 threads = 4 waves, no LDS, no barriers. Wave w covers queries
// [w*64, w*64+64) x all CB candidates of the block. B fragments loaded
// directly from global (fp32) and packed to bf16 in-register; the 4 waves'
// redundant reads of the same 64 KB hit L1/L2.
__global__ __launch_bounds__(256, 3) void score_mfma_kernel(
    const unsigned short* __restrict__ Abf,  // [256][128] bf16
    const float* __restrict__ bank,          // [n][128] f32
    int n, int NT,
    float* __restrict__ tilemax) {           // [256][NT]
  const int t = threadIdx.x;
  const int base = blockIdx.x * CB;
  const int wave = t >> 6;
  const int lane = t & 63;
  const int quad = lane >> 4;       // 0..3
  const int lh   = lane & 15;       // 0..15
  const int q0   = wave * 64;

  // ---- cache A fragments in registers: 4 q-blocks x 4 k-steps (64 VGPR) ----
  s16x8 afr[4][4];
#pragma unroll
  for (int qb = 0; qb < 4; ++qb)
#pragma unroll
    for (int k = 0; k < 4; ++k)
      afr[qb][k] = *(const s16x8*)(Abf + (size_t)(q0 + qb * 16 + lh) * 128 + k * 32 + quad * 8);

  const float4 z4 = make_float4(0.f, 0.f, 0.f, 0.f);

#pragma unroll
  for (int tl = 0; tl < 2; ++tl) {
    int tile_g = blockIdx.x * 2 + tl;
    f32x4 vmax[4];
#pragma unroll
    for (int qb = 0; qb < 4; ++qb) vmax[qb] = f32x4{-FLT_MAX, -FLT_MAX, -FLT_MAX, -FLT_MAX};

#pragma unroll
    for (int cb = 0; cb < 4; ++cb) {
      // this lane serves bank row `crow` as B column lh (of the 16-col group)
      int crow = base + tl * 64 + cb * 16 + lh;
      bool ok = crow < n;
      const float* rp = bank + (size_t)crow * 128 + quad * 8;
      float4 fa[4], fb[4];
#pragma unroll
      for (int k = 0; k < 4; ++k) {
        fa[k] = ok ? *(const float4*)(rp + k * 32)     : z4;
        fb[k] = ok ? *(const float4*)(rp + k * 32 + 4) : z4;
      }
      s16x8 bfr[4];
#pragma unroll
      for (int k = 0; k < 4; ++k) bfr[k] = pack_bf16(fa[k], fb[k]);

#pragma unroll
      for (int qb = 0; qb < 4; ++qb) {
        f32x4 acc = {0.f, 0.f, 0.f, 0.f};
#pragma unroll
        for (int k = 0; k < 4; ++k)
          acc = __builtin_amdgcn_mfma_f32_16x16x32_bf16(afr[qb][k], bfr[k], acc, 0, 0, 0);
#pragma unroll
        for (int r = 0; r < 4; ++r) vmax[qb][r] = fmaxf(vmax[qb][r], acc[r]);
      }
    }

    // reduce max across the 16 candidate columns (lanes lh=0..15 within quad)
    if (tile_g < NT) {
#pragma unroll
      for (int qb = 0; qb < 4; ++qb) {
#pragma unroll
        for (int r = 0; r < 4; ++r) {
          float v = vmax[qb][r];
          v = fmaxf(v, __shfl_xor(v, 1, 64));
          v = fmaxf(v, __shfl_xor(v, 2, 64));
          v = fmaxf(v, __shfl_xor(v, 4, 64));
          v = fmaxf(v, __shfl_xor(v, 8, 64));
          if (lh == 0)
            tilemax[(size_t)(q0 + qb * 16 + quad * 4 + r) * NT + tile_g] = v;
        }
      }
    }
  }
}

// ---------------- block-wide MSB-first radix select --------------------------
struct RadixSM {
  int hist[4][256];   // per-wave replicated histograms (less atomic contention)
  int ss[256];        // suffix-sum scan buffer
  unsigned prefix;
  int t;
};

__device__ __forceinline__ void radix_select(const unsigned* __restrict__ key,
                                             int N, int target, int tid,
                                             RadixSM* sm,
                                             unsigned* outK, int* out_tres) {
  if (tid == 0) { sm->prefix = 0u; sm->t = target; }
  __syncthreads();
  const int wv = tid >> 6;
  for (int r = 0; r < 4; ++r) {
    const int shift = 24 - 8 * r;
    const unsigned kmask = (r == 0) ? 0u : (0xFFFFFFFFu << (32 - 8 * r));
    sm->hist[0][tid] = 0; sm->hist[1][tid] = 0;
    sm->hist[2][tid] = 0; sm->hist[3][tid] = 0;
    __syncthreads();
    const unsigned pref = sm->prefix;
    for (int i = tid; i < N; i += 256) {
      unsigned k = key[i];
      if ((k & kmask) == pref) atomicAdd(&sm->hist[wv][(k >> shift) & 255], 1);
    }
    __syncthreads();
    // inclusive suffix scan over 256 bins (Hillis-Steele, in place)
    int v = sm->hist[0][tid] + sm->hist[1][tid] + sm->hist[2][tid] + sm->hist[3][tid];
    sm->ss[tid] = v;
    __syncthreads();
    for (int d = 1; d < 256; d <<= 1) {
      int add = (tid + d < 256) ? sm->ss[tid + d] : 0;
      __syncthreads();
      v += add;
      sm->ss[tid] = v;
      __syncthreads();
    }
    // v == ss[tid] == #active keys with byte >= tid
    const int tcur = sm->t;
    const int hiCnt = (tid < 255) ? sm->ss[tid + 1] : 0;
    __syncthreads();   // everyone read sm->t / ss before the winner writes
    if (v >= tcur && hiCnt < tcur) {   // unique winner bin (ss monotone)
      sm->prefix = pref | ((unsigned)tid << shift);
      sm->t = tcur - hiCnt;
    }
    __syncthreads();
  }
  *outK = sm->prefix;
  *out_tres = sm->t;
}

// ---------------- F1: per-query exact top-TSEL tiles via radix select --------
__global__ __launch_bounds__(256) void select_tiles_kernel(
    const float* __restrict__ tilemax,  // [256][NT]
    int NT,
    int* __restrict__ sel_g) {          // [256][TSEL] (unordered set)
  const int q = blockIdx.x;
  const int t = threadIdx.x;
  __shared__ unsigned key[NT_MAX];      // ~31 KB
  __shared__ RadixSM rsm;
  __shared__ int n_hi, n_eq;
  __shared__ int eqs[EQCAP];

  // Hardening: every sel slot holds a valid tile index even in the
  // (astronomically unlikely) >EQCAP-tie truncation case.
  if (t < TSEL) sel_g[(size_t)q * TSEL + t] = 0;

  for (int i = t; i < NT; i += 256)
    key[i] = f2key(tilemax[(size_t)q * NT + i]);
  if (t == 0) { n_hi = 0; n_eq = 0; }
  __syncthreads();

  unsigned K; int tres;
  radix_select(key, NT, TSEL, t, &rsm, &K, &tres);

  // emit: all keys > K (exactly TSEL - tres of them), plus the (tres)
  // smallest-index ties at == K.
  for (int i = t; i < NT; i += 256) {
    unsigned k = key[i];
    if (k > K) {
      int p = atomicAdd(&n_hi, 1);
      if (p < TSEL) sel_g[(size_t)q * TSEL + p] = i;
    } else if (k == K) {
      int p = atomicAdd(&n_eq, 1);
      if (p < EQCAP) eqs[p] = i;
    }
  }
  __syncthreads();
  const int nh = n_hi < TSEL ? n_hi : TSEL;   // == TSEL - tres
  const int ne = n_eq < EQCAP ? n_eq : EQCAP;
  if (t < ne) {
    int mine = eqs[t];
    int rank = 0;
    for (int j = 0; j < ne; ++j) rank += (eqs[j] < mine) ? 1 : 0;
    if (rank < tres && nh + rank < TSEL)
      sel_g[(size_t)q * TSEL + nh + rank] = mine;
  }
}

// ---------------- F2: exact fp32 rescore, 16 blocks per query ----------------
// grid = 4096 (1-D): q = bid>>4, part = bid&15. One candidate per thread.
__global__ __launch_bounds__(256) void rescore_kernel(
    const float* __restrict__ A,        // [256][128] fp32 queries (exact)
    const float* __restrict__ bank,     // [n][128]
    int n,
    const int* __restrict__ sel_g,      // [256][TSEL]
    float* __restrict__ sc) {           // [256][TSEL*TILE]
  const int q = blockIdx.x >> 4;
  const int part = blockIdx.x & 15;
  const int t = threadIdx.x;
  __shared__ __align__(16) float aq[128];
  __shared__ int tiles[4];
  if (t < 128) aq[t] = A[(size_t)q * 128 + t];
  if (t >= 128 && t < 132)
    tiles[t - 128] = sel_g[(size_t)q * TSEL + part * 4 + (t - 128)];
  __syncthreads();

  const int tile = tiles[t >> 6];
  const int cand = tile * TILE + (t & 63);
  float s = -FLT_MAX;
  if (cand >= 0 && cand < n) {
    const float* row = bank + (size_t)cand * 128;
    float a0 = 0.f, a1 = 0.f;
#pragma unroll
    for (int i = 0; i < 128; i += 8) {
      float4 b0 = *(const float4*)(row + i);
      float4 b1 = *(const float4*)(row + i + 4);
      float4 x0 = *(const float4*)(aq + i);
      float4 x1 = *(const float4*)(aq + i + 4);
      a0 += x0.x * b0.x + x0.y * b0.y + x0.z * b0.z + x0.w * b0.w;
      a1 += x1.x * b1.x + x1.y * b1.y + x1.z * b1.z + x1.w * b1.w;
    }
    s = a0 + a1;
  }
  sc[(size_t)q * (TSEL * TILE) + part * 256 + t] = s;
}

// ---------------- F3: exact ordered top-KSEL of the 4096 rescored ------------
__global__ __launch_bounds__(256) void topk_kernel(
    const int* __restrict__ sel_g,      // [256][TSEL]
    const float* __restrict__ sc,       // [256][TSEL*TILE]
    int* __restrict__ out) {            // [256][KSEL]
  const int q = blockIdx.x;
  const int t = threadIdx.x;
  __shared__ unsigned key[TSEL * TILE]; // 16 KB
  __shared__ int sel_s[TSEL];
  __shared__ RadixSM rsm;
  __shared__ int n_pool;
  __shared__ int poolc[POOLCAP];
  __shared__ unsigned poolk[POOLCAP];

  if (t < TSEL) sel_s[t] = sel_g[(size_t)q * TSEL + t];
  for (int j = t; j < TSEL * TILE; j += 256)
    key[j] = f2key(sc[(size_t)q * (TSEL * TILE) + j]);
  if (t == 0) n_pool = 0;
  __syncthreads();

  unsigned K; int tres;
  radix_select(key, TSEL * TILE, KSEL, t, &rsm, &K, &tres);
  (void)tres;

  // pool = everything >= K (includes all boundary ties; ranks settle ties)
  for (int j = t; j < TSEL * TILE; j += 256) {
    unsigned k = key[j];
    if (k >= K) {
      int p = atomicAdd(&n_pool, 1);
      if (p < POOLCAP) {
        poolk[p] = k;
        poolc[p] = sel_s[j >> 6] * TILE + (j & 63);
      }
    }
  }
  __syncthreads();
  const int np = n_pool < POOLCAP ? n_pool : POOLCAP;
  if (t < np) {
    unsigned mk = poolk[t];
    int mc = poolc[t];
    int rank = 0;
    for (int j = 0; j < np; ++j) {
      unsigned k = poolk[j];
      int c = poolc[j];
      rank += (k > mk || (k == mk && c < mc)) ? 1 : 0;
    }
    if (rank < KSEL) out[(size_t)q * KSEL + rank] = mc;   // value desc, cand asc
  }
}

// ---------------- gather + mean (fp32 exact) + bf16 copy ---------------------
__global__ void mean_gather_kernel(
    const float* __restrict__ bank,    // enc_ctx
    const int* __restrict__ ixs,       // [256][KSEL]
    float* __restrict__ outA,          // [256][128] fp32
    unsigned short* __restrict__ outAbf) { // [256][128] bf16
  const int q = blockIdx.x;
  const int d = threadIdx.x;           // 128
  float s = 0.f;
  for (int j = 0; j < KSEL; ++j)
    s += bank[(size_t)ixs[q * KSEL + j] * 128 + d];
  s *= (1.0f / 32.0f);
  outA[(size_t)q * 128 + d] = s;
  outAbf[(size_t)q * 128 + d] = (unsigned short)(__float_as_uint(s) >> 16);
}

extern "C" void kernel_launch(void* const* d_in, const int* in_sizes, int n_in,
                              void* d_out, int out_size, void* d_ws, size_t ws_size,
                              hipStream_t stream) {
  const float* contexts = (const float*)d_in[0];
  const float* enc_ans  = (const float*)d_in[1];
  const float* enc_ctx  = (const float*)d_in[2];
  const int n_ans = in_sizes[1] / 128;
  const int n_ctx = in_sizes[2] / 128;
  const int NT_ctx = (n_ctx + TILE - 1) / TILE;
  const int NT_ans = (n_ans + TILE - 1) / TILE;
  const int NT_big = NT_ctx > NT_ans ? NT_ctx : NT_ans;
  const int NB_ctx = (n_ctx + CB - 1) / CB;
  const int NB_ans = (n_ans + CB - 1) / CB;

  // Workspace layout — byte-identical footprint to the round-0 kernel:
  // tilemax | c_ixs | new_ctx | Abf1 | Abf2.
  //   * sc    aliases tilemax (consumed by select_tiles before rescore writes).
  //   * sel_g aliases Abf1 (disjoint lifetimes under stream order).
  char* ws = (char*)d_ws;
  size_t off = 0;
  float* tilemax = (float*)(ws + off);
  off += ((size_t)256 * NT_big * 4 + 255) & ~(size_t)255;
  int* c_ixs = (int*)(ws + off);
  off += ((size_t)256 * KSEL * 4 + 255) & ~(size_t)255;
  float* new_ctx = (float*)(ws + off);
  off += ((size_t)256 * 128 * 4 + 255) & ~(size_t)255;
  unsigned short* Abf1 = (unsigned short*)(ws + off);
  off += ((size_t)256 * 128 * 2 + 255) & ~(size_t)255;
  unsigned short* Abf2 = (unsigned short*)(ws + off);

  float* sc = tilemax;                 // 4 MB <= 8 MB region
  int* sel_g = (int*)Abf1;             // 256*64*4 = 65536 B == Abf1 size

  // ---- hop 1 ----
  cvt_a_kernel<<<128, 256, 0, stream>>>(contexts, Abf1, 256 * 128);
  score_mfma_kernel<<<NB_ctx, 256, 0, stream>>>(Abf1, enc_ctx, n_ctx, NT_ctx, tilemax);
  select_tiles_kernel<<<256, 256, 0, stream>>>(tilemax, NT_ctx, sel_g);
  rescore_kernel<<<4096, 256, 0, stream>>>(contexts, enc_ctx, n_ctx, sel_g, sc);
  topk_kernel<<<256, 256, 0, stream>>>(sel_g, sc, c_ixs);
  mean_gather_kernel<<<256, 128, 0, stream>>>(enc_ctx, c_ixs, new_ctx, Abf2);

  // ---- hop 2 ----
  score_mfma_kernel<<<NB_ans, 256, 0, stream>>>(Abf2, enc_ans, n_ans, NT_ans, tilemax);
  select_tiles_kernel<<<256, 256, 0, stream>>>(tilemax, NT_ans, sel_g);
  rescore_kernel<<<4096, 256, 0, stream>>>(new_ctx, enc_ans, n_ans, sel_g, sc);
  topk_kernel<<<256, 256, 0, stream>>>(sel_g, sc, (int*)d_out);
}

// Round 5
// 1835.879 us; speedup vs baseline: 1.0242x; 1.0242x over previous
//
#include <hip/hip_runtime.h>
#include <hip/hip_bf16.h>
#include <float.h>

// OneHopRanker on MI355X — round 7: pipelined score_mfma (revert of round-6).
// Round-6 post-mortem: LDS-free B loads = 16 lines/instr + 4x wave redundancy
// -> 8x per-CU cache-line request rate -> 655us with every pipe idle. Revert
// to ONE coalesced staging stream; hide its latency with a 2-phase
// double-buffered pipeline (T14 issue-early/write-late + grid-stride chunks):
//   prologue: load chunk c -> regs -> pack -> LDS buf0
//   loop:     issue loads(c+stride) | compute buf[cur] | barrier |
//             pack+write buf[cur^1] | barrier | swap
// Arithmetic bit-identical to the 914us round-5 kernel (same >>16 pack, same
// cb/k/fmax/shuffle order) -> absmax 0. All other kernels byte-identical.

#define TILE 64        // candidates per max-tile == pipeline chunk
#define KSEL 32        // final top-k
#define TSEL 64        // tiles selected per query for exact rescore
#define LROW 136       // LDS row stride in bf16 elems (272 B)
#define NT_MAX 7936    // >= ceil(500000/64)=7813
#define EQCAP 256      // tie-list capacity (radix boundary ties)
#define POOLCAP 256    // final top-k pool capacity
#define SGRID 1024     // score_mfma grid (grid-stride over chunks)

typedef __attribute__((ext_vector_type(8))) short s16x8;   // 8 bf16 (4 VGPRs)
typedef __attribute__((ext_vector_type(4))) float f32x4;

// float -> order-preserving unsigned key (larger float => larger key)
__device__ __forceinline__ unsigned f2key(float f) {
  unsigned u = __float_as_uint(f);
  return (u & 0x80000000u) ? ~u : (u | 0x80000000u);
}

// ---------------- fp32 -> bf16 (truncation) query conversion ----------------
__global__ void cvt_a_kernel(const float* __restrict__ A,
                             unsigned short* __restrict__ Abf, int nelem) {
  int i = blockIdx.x * 256 + threadIdx.x;
  if (i < nelem) Abf[i] = (unsigned short)(__float_as_uint(A[i]) >> 16);
}

// ---------------- stage 1: fused bf16 GEMM + per-tile max (PIPELINED) -------
// 256 threads = 4 waves; wave w serves queries [w*64, w*64+64) as 4 q-blocks
// of 16. Each block grid-strides over 64-row chunks (1 chunk = 1 tile).
// Double-buffered LDS (2 x 64 x LROW bf16 = 34 KB), reg-staged coalesced
// loads issued one chunk ahead.
__global__ __launch_bounds__(256, 3) void score_mfma_kernel(
    const unsigned short* __restrict__ Abf,  // [256][128] bf16
    const float* __restrict__ bank,          // [n][128] f32
    int n, int NT,                           // NT == ceil(n/64) == #chunks
    float* __restrict__ tilemax) {           // [256][NT]
  __shared__ unsigned short bsm[2][TILE * LROW];
  const int t = threadIdx.x;
  const int wave = t >> 6;
  const int lane = t & 63;
  const int quad = lane >> 4;       // 0..3
  const int lh   = lane & 15;       // 0..15
  const int q0   = wave * 64;
  const float4 z4 = make_float4(0.f, 0.f, 0.f, 0.f);

  // ---- A fragments in registers: 4 q-blocks x 4 k-steps (64 VGPR), once ----
  s16x8 afr[4][4];
#pragma unroll
  for (int qb = 0; qb < 4; ++qb)
#pragma unroll
    for (int k = 0; k < 4; ++k)
      afr[qb][k] = *(const s16x8*)(Abf + (size_t)(q0 + qb * 16 + lh) * 128 + k * 32 + quad * 8);

  // staging registers: 64 rows x 32 float4 = 2048 float4 / 256 thr = 8/thread
  float4 st[8];

#define SCORE_LOAD(cc)                                                         \
  {                                                                            \
    _Pragma("unroll")                                                          \
    for (int i = 0; i < 8; ++i) {                                              \
      int idx = t + i * 256;                                                   \
      int row = idx >> 5, c4 = idx & 31;                                       \
      int g = (cc) * TILE + row;                                               \
      st[i] = (g < n) ? *(const float4*)(bank + (size_t)g * 128 + c4 * 4) : z4;\
    }                                                                          \
  }

#define SCORE_PACKWRITE(bb)                                                    \
  {                                                                            \
    _Pragma("unroll")                                                          \
    for (int i = 0; i < 8; ++i) {                                              \
      int idx = t + i * 256;                                                   \
      int row = idx >> 5, c4 = idx & 31;                                       \
      unsigned p0 = (__float_as_uint(st[i].y) & 0xffff0000u) |                 \
                    (__float_as_uint(st[i].x) >> 16);                          \
      unsigned p1 = (__float_as_uint(st[i].w) & 0xffff0000u) |                 \
                    (__float_as_uint(st[i].z) >> 16);                          \
      *(uint2*)(&bsm[(bb)][row * LROW + c4 * 4]) = make_uint2(p0, p1);         \
    }                                                                          \
  }

  int c = blockIdx.x;
  int cur = 0;
  // ---- prologue: stage chunk c into buf0 ----
  if (c < NT) {
    SCORE_LOAD(c);
    SCORE_PACKWRITE(0);
  }
  __syncthreads();

  while (c < NT) {
    const int cn = c + (int)gridDim.x;
    const bool haveN = cn < NT;
    if (haveN) SCORE_LOAD(cn);     // issue next chunk's loads (in flight
                                   // during compute; waited at packwrite)

    // ---- compute chunk c from bsm[cur]: 1 tile of 64 candidates ----
    f32x4 vmax[4];
#pragma unroll
    for (int qb = 0; qb < 4; ++qb)
      vmax[qb] = f32x4{-FLT_MAX, -FLT_MAX, -FLT_MAX, -FLT_MAX};

#pragma unroll
    for (int cbi = 0; cbi < 4; ++cbi) {
      const unsigned short* bp = &bsm[cur][(cbi * 16 + lh) * LROW + quad * 8];
      s16x8 bfr[4];
#pragma unroll
      for (int k = 0; k < 4; ++k) bfr[k] = *(const s16x8*)(bp + k * 32);
#pragma unroll
      for (int qb = 0; qb < 4; ++qb) {
        f32x4 acc = {0.f, 0.f, 0.f, 0.f};
#pragma unroll
        for (int k = 0; k < 4; ++k)
          acc = __builtin_amdgcn_mfma_f32_16x16x32_bf16(afr[qb][k], bfr[k], acc, 0, 0, 0);
#pragma unroll
        for (int r = 0; r < 4; ++r) vmax[qb][r] = fmaxf(vmax[qb][r], acc[r]);
      }
    }

    // reduce max across the 16 candidate columns; store tile c
#pragma unroll
    for (int qb = 0; qb < 4; ++qb) {
#pragma unroll
      for (int r = 0; r < 4; ++r) {
        float v = vmax[qb][r];
        v = fmaxf(v, __shfl_xor(v, 1, 64));
        v = fmaxf(v, __shfl_xor(v, 2, 64));
        v = fmaxf(v, __shfl_xor(v, 4, 64));
        v = fmaxf(v, __shfl_xor(v, 8, 64));
        if (lh == 0)
          tilemax[(size_t)(q0 + qb * 16 + quad * 4 + r) * NT + c] = v;
      }
    }

    __syncthreads();               // all waves done reading bsm[cur^1]'s era
    if (haveN) SCORE_PACKWRITE(cur ^ 1);   // vmcnt drain happens here
    __syncthreads();               // staged data visible for next compute
    cur ^= 1;
    c = cn;
  }
#undef SCORE_LOAD
#undef SCORE_PACKWRITE
}

// ---------------- block-wide MSB-first radix select --------------------------
struct RadixSM {
  int hist[4][256];   // per-wave replicated histograms (less atomic contention)
  int ss[256];        // suffix-sum scan buffer
  unsigned prefix;
  int t;
};

__device__ __forceinline__ void radix_select(const unsigned* __restrict__ key,
                                             int N, int target, int tid,
                                             RadixSM* sm,
                                             unsigned* outK, int* out_tres) {
  if (tid == 0) { sm->prefix = 0u; sm->t = target; }
  __syncthreads();
  const int wv = tid >> 6;
  for (int r = 0; r < 4; ++r) {
    const int shift = 24 - 8 * r;
    const unsigned kmask = (r == 0) ? 0u : (0xFFFFFFFFu << (32 - 8 * r));
    sm->hist[0][tid] = 0; sm->hist[1][tid] = 0;
    sm->hist[2][tid] = 0; sm->hist[3][tid] = 0;
    __syncthreads();
    const unsigned pref = sm->prefix;
    for (int i = tid; i < N; i += 256) {
      unsigned k = key[i];
      if ((k & kmask) == pref) atomicAdd(&sm->hist[wv][(k >> shift) & 255], 1);
    }
    __syncthreads();
    // inclusive suffix scan over 256 bins (Hillis-Steele, in place)
    int v = sm->hist[0][tid] + sm->hist[1][tid] + sm->hist[2][tid] + sm->hist[3][tid];
    sm->ss[tid] = v;
    __syncthreads();
    for (int d = 1; d < 256; d <<= 1) {
      int add = (tid + d < 256) ? sm->ss[tid + d] : 0;
      __syncthreads();
      v += add;
      sm->ss[tid] = v;
      __syncthreads();
    }
    // v == ss[tid] == #active keys with byte >= tid
    const int tcur = sm->t;
    const int hiCnt = (tid < 255) ? sm->ss[tid + 1] : 0;
    __syncthreads();   // everyone read sm->t / ss before the winner writes
    if (v >= tcur && hiCnt < tcur) {   // unique winner bin (ss monotone)
      sm->prefix = pref | ((unsigned)tid << shift);
      sm->t = tcur - hiCnt;
    }
    __syncthreads();
  }
  *outK = sm->prefix;
  *out_tres = sm->t;
}

// ---------------- F1: per-query exact top-TSEL tiles via radix select --------
__global__ __launch_bounds__(256) void select_tiles_kernel(
    const float* __restrict__ tilemax,  // [256][NT]
    int NT,
    int* __restrict__ sel_g) {          // [256][TSEL] (unordered set)
  const int q = blockIdx.x;
  const int t = threadIdx.x;
  __shared__ unsigned key[NT_MAX];      // ~31 KB
  __shared__ RadixSM rsm;
  __shared__ int n_hi, n_eq;
  __shared__ int eqs[EQCAP];

  // Hardening: every sel slot holds a valid tile index even in the
  // (astronomically unlikely) >EQCAP-tie truncation case.
  if (t < TSEL) sel_g[(size_t)q * TSEL + t] = 0;

  for (int i = t; i < NT; i += 256)
    key[i] = f2key(tilemax[(size_t)q * NT + i]);
  if (t == 0) { n_hi = 0; n_eq = 0; }
  __syncthreads();

  unsigned K; int tres;
  radix_select(key, NT, TSEL, t, &rsm, &K, &tres);

  // emit: all keys > K (exactly TSEL - tres of them), plus the (tres)
  // smallest-index ties at == K.
  for (int i = t; i < NT; i += 256) {
    unsigned k = key[i];
    if (k > K) {
      int p = atomicAdd(&n_hi, 1);
      if (p < TSEL) sel_g[(size_t)q * TSEL + p] = i;
    } else if (k == K) {
      int p = atomicAdd(&n_eq, 1);
      if (p < EQCAP) eqs[p] = i;
    }
  }
  __syncthreads();
  const int nh = n_hi < TSEL ? n_hi : TSEL;   // == TSEL - tres
  const int ne = n_eq < EQCAP ? n_eq : EQCAP;
  if (t < ne) {
    int mine = eqs[t];
    int rank = 0;
    for (int j = 0; j < ne; ++j) rank += (eqs[j] < mine) ? 1 : 0;
    if (rank < tres && nh + rank < TSEL)
      sel_g[(size_t)q * TSEL + nh + rank] = mine;
  }
}

// ---------------- F2: exact fp32 rescore, 16 blocks per query ----------------
// grid = 4096 (1-D): q = bid>>4, part = bid&15. One candidate per thread.
__global__ __launch_bounds__(256) void rescore_kernel(
    const float* __restrict__ A,        // [256][128] fp32 queries (exact)
    const float* __restrict__ bank,     // [n][128]
    int n,
    const int* __restrict__ sel_g,      // [256][TSEL]
    float* __restrict__ sc) {           // [256][TSEL*TILE]
  const int q = blockIdx.x >> 4;
  const int part = blockIdx.x & 15;
  const int t = threadIdx.x;
  __shared__ __align__(16) float aq[128];
  __shared__ int tiles[4];
  if (t < 128) aq[t] = A[(size_t)q * 128 + t];
  if (t >= 128 && t < 132)
    tiles[t - 128] = sel_g[(size_t)q * TSEL + part * 4 + (t - 128)];
  __syncthreads();

  const int tile = tiles[t >> 6];
  const int cand = tile * TILE + (t & 63);
  float s = -FLT_MAX;
  if (cand >= 0 && cand < n) {
    const float* row = bank + (size_t)cand * 128;
    float a0 = 0.f, a1 = 0.f;
#pragma unroll
    for (int i = 0; i < 128; i += 8) {
      float4 b0 = *(const float4*)(row + i);
      float4 b1 = *(const float4*)(row + i + 4);
      float4 x0 = *(const float4*)(aq + i);
      float4 x1 = *(const float4*)(aq + i + 4);
      a0 += x0.x * b0.x + x0.y * b0.y + x0.z * b0.z + x0.w * b0.w;
      a1 += x1.x * b1.x + x1.y * b1.y + x1.z * b1.z + x1.w * b1.w;
    }
    s = a0 + a1;
  }
  sc[(size_t)q * (TSEL * TILE) + part * 256 + t] = s;
}

// ---------------- F3: exact ordered top-KSEL of the 4096 rescored ------------
__global__ __launch_bounds__(256) void topk_kernel(
    const int* __restrict__ sel_g,      // [256][TSEL]
    const float* __restrict__ sc,       // [256][TSEL*TILE]
    int* __restrict__ out) {            // [256][KSEL]
  const int q = blockIdx.x;
  const int t = threadIdx.x;
  __shared__ unsigned key[TSEL * TILE]; // 16 KB
  __shared__ int sel_s[TSEL];
  __shared__ RadixSM rsm;
  __shared__ int n_pool;
  __shared__ int poolc[POOLCAP];
  __shared__ unsigned poolk[POOLCAP];

  if (t < TSEL) sel_s[t] = sel_g[(size_t)q * TSEL + t];
  for (int j = t; j < TSEL * TILE; j += 256)
    key[j] = f2key(sc[(size_t)q * (TSEL * TILE) + j]);
  if (t == 0) n_pool = 0;
  __syncthreads();

  unsigned K; int tres;
  radix_select(key, TSEL * TILE, KSEL, t, &rsm, &K, &tres);
  (void)tres;

  // pool = everything >= K (includes all boundary ties; ranks settle ties)
  for (int j = t; j < TSEL * TILE; j += 256) {
    unsigned k = key[j];
    if (k >= K) {
      int p = atomicAdd(&n_pool, 1);
      if (p < POOLCAP) {
        poolk[p] = k;
        poolc[p] = sel_s[j >> 6] * TILE + (j & 63);
      }
    }
  }
  __syncthreads();
  const int np = n_pool < POOLCAP ? n_pool : POOLCAP;
  if (t < np) {
    unsigned mk = poolk[t];
    int mc = poolc[t];
    int rank = 0;
    for (int j = 0; j < np; ++j) {
      unsigned k = poolk[j];
      int c = poolc[j];
      rank += (k > mk || (k == mk && c < mc)) ? 1 : 0;
    }
    if (rank < KSEL) out[(size_t)q * KSEL + rank] = mc;   // value desc, cand asc
  }
}

// ---------------- gather + mean (fp32 exact) + bf16 copy ---------------------
__global__ void mean_gather_kernel(
    const float* __restrict__ bank,    // enc_ctx
    const int* __restrict__ ixs,       // [256][KSEL]
    float* __restrict__ outA,          // [256][128] fp32
    unsigned short* __restrict__ outAbf) { // [256][128] bf16
  const int q = blockIdx.x;
  const int d = threadIdx.x;           // 128
  float s = 0.f;
  for (int j = 0; j < KSEL; ++j)
    s += bank[(size_t)ixs[q * KSEL + j] * 128 + d];
  s *= (1.0f / 32.0f);
  outA[(size_t)q * 128 + d] = s;
  outAbf[(size_t)q * 128 + d] = (unsigned short)(__float_as_uint(s) >> 16);
}

extern "C" void kernel_launch(void* const* d_in, const int* in_sizes, int n_in,
                              void* d_out, int out_size, void* d_ws, size_t ws_size,
                              hipStream_t stream) {
  const float* contexts = (const float*)d_in[0];
  const float* enc_ans  = (const float*)d_in[1];
  const float* enc_ctx  = (const float*)d_in[2];
  const int n_ans = in_sizes[1] / 128;
  const int n_ctx = in_sizes[2] / 128;
  const int NT_ctx = (n_ctx + TILE - 1) / TILE;
  const int NT_ans = (n_ans + TILE - 1) / TILE;
  const int NT_big = NT_ctx > NT_ans ? NT_ctx : NT_ans;

  // Workspace layout — byte-identical footprint to the round-0 kernel:
  // tilemax | c_ixs | new_ctx | Abf1 | Abf2.
  //   * sc    aliases tilemax (consumed by select_tiles before rescore writes).
  //   * sel_g aliases Abf1 (disjoint lifetimes under stream order).
  char* ws = (char*)d_ws;
  size_t off = 0;
  float* tilemax = (float*)(ws + off);
  off += ((size_t)256 * NT_big * 4 + 255) & ~(size_t)255;
  int* c_ixs = (int*)(ws + off);
  off += ((size_t)256 * KSEL * 4 + 255) & ~(size_t)255;
  float* new_ctx = (float*)(ws + off);
  off += ((size_t)256 * 128 * 4 + 255) & ~(size_t)255;
  unsigned short* Abf1 = (unsigned short*)(ws + off);
  off += ((size_t)256 * 128 * 2 + 255) & ~(size_t)255;
  unsigned short* Abf2 = (unsigned short*)(ws + off);

  float* sc = tilemax;                 // 4 MB <= 8 MB region
  int* sel_g = (int*)Abf1;             // 256*64*4 = 65536 B == Abf1 size

  // ---- hop 1 ----
  cvt_a_kernel<<<128, 256, 0, stream>>>(contexts, Abf1, 256 * 128);
  score_mfma_kernel<<<SGRID, 256, 0, stream>>>(Abf1, enc_ctx, n_ctx, NT_ctx, tilemax);
  select_tiles_kernel<<<256, 256, 0, stream>>>(tilemax, NT_ctx, sel_g);
  rescore_kernel<<<4096, 256, 0, stream>>>(contexts, enc_ctx, n_ctx, sel_g, sc);
  topk_kernel<<<256, 256, 0, stream>>>(sel_g, sc, c_ixs);
  mean_gather_kernel<<<256, 128, 0, stream>>>(enc_ctx, c_ixs, new_ctx, Abf2);

  // ---- hop 2 ----
  score_mfma_kernel<<<SGRID, 256, 0, stream>>>(Abf2, enc_ans, n_ans, NT_ans, tilemax);
  select_tiles_kernel<<<256, 256, 0, stream>>>(tilemax, NT_ans, sel_g);
  rescore_kernel<<<4096, 256, 0, stream>>>(new_ctx, enc_ans, n_ans, sel_g, sc);
  topk_kernel<<<256, 256, 0, stream>>>(sel_g, sc, (int*)d_out);
}

// Round 6
// 909.432 us; speedup vs baseline: 2.0677x; 2.0187x over previous
//
#include <hip/hip_runtime.h>
#include <hip/hip_bf16.h>
#include <float.h>

// OneHopRanker on MI355X — round 8: DMA-staged score_mfma.
// Round-7 post-mortem: reg-staged double-buffer spilled st[8] to scratch
// (VGPR 84 < live set) -> ~1 GB of scratch HBM traffic per dispatch
// (FETCH 674 MB / WRITE 816 MB vs logical 264 MB). Fix: stage via
// __builtin_amdgcn_global_load_lds (async DMA, zero VGPRs, nothing to spill),
// fp32 linear [64][128] LDS (DMA needs linear dest), bf16 truncation moved to
// fragment-read (same >>16 pack -> tilemax bit-identical). Double-buffered
// 2-phase: stage(next) | compute(cur) | __syncthreads (implicit vmcnt drain).
// Blocks own contiguous tile ranges. All other kernels byte-identical.

#define TILE 64        // candidates per max-tile == pipeline chunk
#define KSEL 32        // final top-k
#define TSEL 64        // tiles selected per query for exact rescore
#define NT_MAX 7936    // >= ceil(500000/64)=7813
#define EQCAP 256      // tie-list capacity (radix boundary ties)
#define POOLCAP 256    // final top-k pool capacity
#define SGRID 512      // score_mfma grid (contiguous tile ranges)

typedef __attribute__((ext_vector_type(8))) short s16x8;   // 8 bf16 (4 VGPRs)
typedef __attribute__((ext_vector_type(4))) float f32x4;

// float -> order-preserving unsigned key (larger float => larger key)
__device__ __forceinline__ unsigned f2key(float f) {
  unsigned u = __float_as_uint(f);
  return (u & 0x80000000u) ? ~u : (u | 0x80000000u);
}

// 8 consecutive fp32 -> 8 bf16 by truncation; bit-identical to the round-3
// staging pack ((y & 0xffff0000) | (x >> 16) on consecutive pairs).
__device__ __forceinline__ s16x8 pack_bf16(float4 a, float4 b) {
  union { s16x8 v; unsigned u[4]; } r;
  r.u[0] = (__float_as_uint(a.y) & 0xffff0000u) | (__float_as_uint(a.x) >> 16);
  r.u[1] = (__float_as_uint(a.w) & 0xffff0000u) | (__float_as_uint(a.z) >> 16);
  r.u[2] = (__float_as_uint(b.y) & 0xffff0000u) | (__float_as_uint(b.x) >> 16);
  r.u[3] = (__float_as_uint(b.w) & 0xffff0000u) | (__float_as_uint(b.z) >> 16);
  return r.v;
}

// async global->LDS DMA, 16 B per lane. Global addr is PER-LANE; LDS addr is
// the wave-uniform base (HW adds lane*16).
__device__ __forceinline__ void async_copy16(const float* g, float* l) {
  __builtin_amdgcn_global_load_lds(
      (const __attribute__((address_space(1))) unsigned int*)g,
      (__attribute__((address_space(3))) unsigned int*)l, 16, 0, 0);
}

// ---------------- fp32 -> bf16 (truncation) query conversion ----------------
__global__ void cvt_a_kernel(const float* __restrict__ A,
                             unsigned short* __restrict__ Abf, int nelem) {
  int i = blockIdx.x * 256 + threadIdx.x;
  if (i < nelem) Abf[i] = (unsigned short)(__float_as_uint(A[i]) >> 16);
}

// ---------------- stage 1: fused bf16 GEMM + per-tile max (DMA-staged) ------
// 256 threads = 4 waves; wave w serves queries [w*64, w*64+64). Each block
// owns a contiguous range of 64-row tiles; LDS fp32 double buffer (2x32 KB)
// filled by global_load_lds one tile ahead.
__global__ __launch_bounds__(256) void score_mfma_kernel(
    const unsigned short* __restrict__ Abf,  // [256][128] bf16
    const float* __restrict__ bank,          // [n][128] f32
    int n, int NT,                           // NT == ceil(n/64)
    float* __restrict__ tilemax) {           // [256][NT]
  __shared__ float bsm[2][TILE * 128];       // 2 x 32 KB, linear [64][128]
  const int t = threadIdx.x;
  const int wave = t >> 6;
  const int lane = t & 63;
  const int quad = lane >> 4;       // 0..3
  const int lh   = lane & 15;       // 0..15
  const int q0   = wave * 64;
  const float4 z4 = make_float4(0.f, 0.f, 0.f, 0.f);

  const int per = (NT + (int)gridDim.x - 1) / (int)gridDim.x;
  const int tt0 = blockIdx.x * per;
  const int tt1 = (tt0 + per < NT) ? tt0 + per : NT;
  if (tt0 >= tt1) return;          // whole block exits: no barrier divergence

  // ---- A fragments in registers: 4 q-blocks x 4 k-steps (64 VGPR), once ----
  s16x8 afr[4][4];
#pragma unroll
  for (int qb = 0; qb < 4; ++qb)
#pragma unroll
    for (int k = 0; k < 4; ++k)
      afr[qb][k] = *(const s16x8*)(Abf + (size_t)(q0 + qb * 16 + lh) * 128 + k * 32 + quad * 8);

  // stage tile `tile` into buffer bb. Full tiles: pure async DMA (no VGPRs).
  // Tail tile (rows beyond n): guarded vector loads + direct LDS writes.
  auto stage = [&](int bb, int tile) {
    if (tile * TILE + TILE <= n) {
      const float* gsrc = bank + (size_t)tile * (TILE * 128);
#pragma unroll
      for (int i = 0; i < 8; ++i) {
        const int seg = wave * 8 + i;        // 32 segments of 1024 B
        async_copy16(gsrc + seg * 256 + lane * 4, &bsm[bb][seg * 256]);
      }
    } else {
#pragma unroll
      for (int i = 0; i < 8; ++i) {
        int idx = t + i * 256;
        int row = idx >> 5, c4 = idx & 31;
        int g = tile * TILE + row;
        float4 v = (g < n) ? *(const float4*)(bank + (size_t)g * 128 + c4 * 4) : z4;
        *(float4*)(&bsm[bb][row * 128 + c4 * 4]) = v;
      }
    }
  };

  int c = tt0, cur = 0;
  stage(0, c);
  __syncthreads();                 // vmcnt(0) drain: buf0 ready

  while (true) {
    if (c + 1 < tt1) stage(cur ^ 1, c + 1);   // async, flies under compute

    // ---- compute tile c from bsm[cur] ----
    f32x4 vmax[4];
#pragma unroll
    for (int qb = 0; qb < 4; ++qb)
      vmax[qb] = f32x4{-FLT_MAX, -FLT_MAX, -FLT_MAX, -FLT_MAX};

#pragma unroll
    for (int cbi = 0; cbi < 4; ++cbi) {
      const float* bp = &bsm[cur][(cbi * 16 + lh) * 128 + quad * 8];
      s16x8 bfr[4];
#pragma unroll
      for (int k = 0; k < 4; ++k) {
        float4 fa = *(const float4*)(bp + k * 32);
        float4 fb = *(const float4*)(bp + k * 32 + 4);
        bfr[k] = pack_bf16(fa, fb);
      }
#pragma unroll
      for (int qb = 0; qb < 4; ++qb) {
        f32x4 acc = {0.f, 0.f, 0.f, 0.f};
#pragma unroll
        for (int k = 0; k < 4; ++k)
          acc = __builtin_amdgcn_mfma_f32_16x16x32_bf16(afr[qb][k], bfr[k], acc, 0, 0, 0);
#pragma unroll
        for (int r = 0; r < 4; ++r) vmax[qb][r] = fmaxf(vmax[qb][r], acc[r]);
      }
    }

    // reduce max across the 16 candidate columns; store tile c
#pragma unroll
    for (int qb = 0; qb < 4; ++qb) {
#pragma unroll
      for (int r = 0; r < 4; ++r) {
        float v = vmax[qb][r];
        v = fmaxf(v, __shfl_xor(v, 1, 64));
        v = fmaxf(v, __shfl_xor(v, 2, 64));
        v = fmaxf(v, __shfl_xor(v, 4, 64));
        v = fmaxf(v, __shfl_xor(v, 8, 64));
        if (lh == 0)
          tilemax[(size_t)(q0 + qb * 16 + quad * 4 + r) * NT + c] = v;
      }
    }

    if (c + 1 >= tt1) break;
    __syncthreads();               // drains next-tile DMA + guards buf reuse
    cur ^= 1;
    ++c;
  }
}

// ---------------- block-wide MSB-first radix select --------------------------
struct RadixSM {
  int hist[4][256];   // per-wave replicated histograms (less atomic contention)
  int ss[256];        // suffix-sum scan buffer
  unsigned prefix;
  int t;
};

__device__ __forceinline__ void radix_select(const unsigned* __restrict__ key,
                                             int N, int target, int tid,
                                             RadixSM* sm,
                                             unsigned* outK, int* out_tres) {
  if (tid == 0) { sm->prefix = 0u; sm->t = target; }
  __syncthreads();
  const int wv = tid >> 6;
  for (int r = 0; r < 4; ++r) {
    const int shift = 24 - 8 * r;
    const unsigned kmask = (r == 0) ? 0u : (0xFFFFFFFFu << (32 - 8 * r));
    sm->hist[0][tid] = 0; sm->hist[1][tid] = 0;
    sm->hist[2][tid] = 0; sm->hist[3][tid] = 0;
    __syncthreads();
    const unsigned pref = sm->prefix;
    for (int i = tid; i < N; i += 256) {
      unsigned k = key[i];
      if ((k & kmask) == pref) atomicAdd(&sm->hist[wv][(k >> shift) & 255], 1);
    }
    __syncthreads();
    // inclusive suffix scan over 256 bins (Hillis-Steele, in place)
    int v = sm->hist[0][tid] + sm->hist[1][tid] + sm->hist[2][tid] + sm->hist[3][tid];
    sm->ss[tid] = v;
    __syncthreads();
    for (int d = 1; d < 256; d <<= 1) {
      int add = (tid + d < 256) ? sm->ss[tid + d] : 0;
      __syncthreads();
      v += add;
      sm->ss[tid] = v;
      __syncthreads();
    }
    // v == ss[tid] == #active keys with byte >= tid
    const int tcur = sm->t;
    const int hiCnt = (tid < 255) ? sm->ss[tid + 1] : 0;
    __syncthreads();   // everyone read sm->t / ss before the winner writes
    if (v >= tcur && hiCnt < tcur) {   // unique winner bin (ss monotone)
      sm->prefix = pref | ((unsigned)tid << shift);
      sm->t = tcur - hiCnt;
    }
    __syncthreads();
  }
  *outK = sm->prefix;
  *out_tres = sm->t;
}

// ---------------- F1: per-query exact top-TSEL tiles via radix select --------
__global__ __launch_bounds__(256) void select_tiles_kernel(
    const float* __restrict__ tilemax,  // [256][NT]
    int NT,
    int* __restrict__ sel_g) {          // [256][TSEL] (unordered set)
  const int q = blockIdx.x;
  const int t = threadIdx.x;
  __shared__ unsigned key[NT_MAX];      // ~31 KB
  __shared__ RadixSM rsm;
  __shared__ int n_hi, n_eq;
  __shared__ int eqs[EQCAP];

  // Hardening: every sel slot holds a valid tile index even in the
  // (astronomically unlikely) >EQCAP-tie truncation case.
  if (t < TSEL) sel_g[(size_t)q * TSEL + t] = 0;

  for (int i = t; i < NT; i += 256)
    key[i] = f2key(tilemax[(size_t)q * NT + i]);
  if (t == 0) { n_hi = 0; n_eq = 0; }
  __syncthreads();

  unsigned K; int tres;
  radix_select(key, NT, TSEL, t, &rsm, &K, &tres);

  // emit: all keys > K (exactly TSEL - tres of them), plus the (tres)
  // smallest-index ties at == K.
  for (int i = t; i < NT; i += 256) {
    unsigned k = key[i];
    if (k > K) {
      int p = atomicAdd(&n_hi, 1);
      if (p < TSEL) sel_g[(size_t)q * TSEL + p] = i;
    } else if (k == K) {
      int p = atomicAdd(&n_eq, 1);
      if (p < EQCAP) eqs[p] = i;
    }
  }
  __syncthreads();
  const int nh = n_hi < TSEL ? n_hi : TSEL;   // == TSEL - tres
  const int ne = n_eq < EQCAP ? n_eq : EQCAP;
  if (t < ne) {
    int mine = eqs[t];
    int rank = 0;
    for (int j = 0; j < ne; ++j) rank += (eqs[j] < mine) ? 1 : 0;
    if (rank < tres && nh + rank < TSEL)
      sel_g[(size_t)q * TSEL + nh + rank] = mine;
  }
}

// ---------------- F2: exact fp32 rescore, 16 blocks per query ----------------
// grid = 4096 (1-D): q = bid>>4, part = bid&15. One candidate per thread.
__global__ __launch_bounds__(256) void rescore_kernel(
    const float* __restrict__ A,        // [256][128] fp32 queries (exact)
    const float* __restrict__ bank,     // [n][128]
    int n,
    const int* __restrict__ sel_g,      // [256][TSEL]
    float* __restrict__ sc) {           // [256][TSEL*TILE]
  const int q = blockIdx.x >> 4;
  const int part = blockIdx.x & 15;
  const int t = threadIdx.x;
  __shared__ __align__(16) float aq[128];
  __shared__ int tiles[4];
  if (t < 128) aq[t] = A[(size_t)q * 128 + t];
  if (t >= 128 && t < 132)
    tiles[t - 128] = sel_g[(size_t)q * TSEL + part * 4 + (t - 128)];
  __syncthreads();

  const int tile = tiles[t >> 6];
  const int cand = tile * TILE + (t & 63);
  float s = -FLT_MAX;
  if (cand >= 0 && cand < n) {
    const float* row = bank + (size_t)cand * 128;
    float a0 = 0.f, a1 = 0.f;
#pragma unroll
    for (int i = 0; i < 128; i += 8) {
      float4 b0 = *(const float4*)(row + i);
      float4 b1 = *(const float4*)(row + i + 4);
      float4 x0 = *(const float4*)(aq + i);
      float4 x1 = *(const float4*)(aq + i + 4);
      a0 += x0.x * b0.x + x0.y * b0.y + x0.z * b0.z + x0.w * b0.w;
      a1 += x1.x * b1.x + x1.y * b1.y + x1.z * b1.z + x1.w * b1.w;
    }
    s = a0 + a1;
  }
  sc[(size_t)q * (TSEL * TILE) + part * 256 + t] = s;
}

// ---------------- F3: exact ordered top-KSEL of the 4096 rescored ------------
__global__ __launch_bounds__(256) void topk_kernel(
    const int* __restrict__ sel_g,      // [256][TSEL]
    const float* __restrict__ sc,       // [256][TSEL*TILE]
    int* __restrict__ out) {            // [256][KSEL]
  const int q = blockIdx.x;
  const int t = threadIdx.x;
  __shared__ unsigned key[TSEL * TILE]; // 16 KB
  __shared__ int sel_s[TSEL];
  __shared__ RadixSM rsm;
  __shared__ int n_pool;
  __shared__ int poolc[POOLCAP];
  __shared__ unsigned poolk[POOLCAP];

  if (t < TSEL) sel_s[t] = sel_g[(size_t)q * TSEL + t];
  for (int j = t; j < TSEL * TILE; j += 256)
    key[j] = f2key(sc[(size_t)q * (TSEL * TILE) + j]);
  if (t == 0) n_pool = 0;
  __syncthreads();

  unsigned K; int tres;
  radix_select(key, TSEL * TILE, KSEL, t, &rsm, &K, &tres);
  (void)tres;

  // pool = everything >= K (includes all boundary ties; ranks settle ties)
  for (int j = t; j < TSEL * TILE; j += 256) {
    unsigned k = key[j];
    if (k >= K) {
      int p = atomicAdd(&n_pool, 1);
      if (p < POOLCAP) {
        poolk[p] = k;
        poolc[p] = sel_s[j >> 6] * TILE + (j & 63);
      }
    }
  }
  __syncthreads();
  const int np = n_pool < POOLCAP ? n_pool : POOLCAP;
  if (t < np) {
    unsigned mk = poolk[t];
    int mc = poolc[t];
    int rank = 0;
    for (int j = 0; j < np; ++j) {
      unsigned k = poolk[j];
      int c = poolc[j];
      rank += (k > mk || (k == mk && c < mc)) ? 1 : 0;
    }
    if (rank < KSEL) out[(size_t)q * KSEL + rank] = mc;   // value desc, cand asc
  }
}

// ---------------- gather + mean (fp32 exact) + bf16 copy ---------------------
__global__ void mean_gather_kernel(
    const float* __restrict__ bank,    // enc_ctx
    const int* __restrict__ ixs,       // [256][KSEL]
    float* __restrict__ outA,          // [256][128] fp32
    unsigned short* __restrict__ outAbf) { // [256][128] bf16
  const int q = blockIdx.x;
  const int d = threadIdx.x;           // 128
  float s = 0.f;
  for (int j = 0; j < KSEL; ++j)
    s += bank[(size_t)ixs[q * KSEL + j] * 128 + d];
  s *= (1.0f / 32.0f);
  outA[(size_t)q * 128 + d] = s;
  outAbf[(size_t)q * 128 + d] = (unsigned short)(__float_as_uint(s) >> 16);
}

extern "C" void kernel_launch(void* const* d_in, const int* in_sizes, int n_in,
                              void* d_out, int out_size, void* d_ws, size_t ws_size,
                              hipStream_t stream) {
  const float* contexts = (const float*)d_in[0];
  const float* enc_ans  = (const float*)d_in[1];
  const float* enc_ctx  = (const float*)d_in[2];
  const int n_ans = in_sizes[1] / 128;
  const int n_ctx = in_sizes[2] / 128;
  const int NT_ctx = (n_ctx + TILE - 1) / TILE;
  const int NT_ans = (n_ans + TILE - 1) / TILE;
  const int NT_big = NT_ctx > NT_ans ? NT_ctx : NT_ans;

  // Workspace layout — byte-identical footprint to the round-0 kernel:
  // tilemax | c_ixs | new_ctx | Abf1 | Abf2.
  //   * sc    aliases tilemax (consumed by select_tiles before rescore writes).
  //   * sel_g aliases Abf1 (disjoint lifetimes under stream order).
  char* ws = (char*)d_ws;
  size_t off = 0;
  float* tilemax = (float*)(ws + off);
  off += ((size_t)256 * NT_big * 4 + 255) & ~(size_t)255;
  int* c_ixs = (int*)(ws + off);
  off += ((size_t)256 * KSEL * 4 + 255) & ~(size_t)255;
  float* new_ctx = (float*)(ws + off);
  off += ((size_t)256 * 128 * 4 + 255) & ~(size_t)255;
  unsigned short* Abf1 = (unsigned short*)(ws + off);
  off += ((size_t)256 * 128 * 2 + 255) & ~(size_t)255;
  unsigned short* Abf2 = (unsigned short*)(ws + off);

  float* sc = tilemax;                 // 4 MB <= 8 MB region
  int* sel_g = (int*)Abf1;             // 256*64*4 = 65536 B == Abf1 size

  // ---- hop 1 ----
  cvt_a_kernel<<<128, 256, 0, stream>>>(contexts, Abf1, 256 * 128);
  score_mfma_kernel<<<SGRID, 256, 0, stream>>>(Abf1, enc_ctx, n_ctx, NT_ctx, tilemax);
  select_tiles_kernel<<<256, 256, 0, stream>>>(tilemax, NT_ctx, sel_g);
  rescore_kernel<<<4096, 256, 0, stream>>>(contexts, enc_ctx, n_ctx, sel_g, sc);
  topk_kernel<<<256, 256, 0, stream>>>(sel_g, sc, c_ixs);
  mean_gather_kernel<<<256, 128, 0, stream>>>(enc_ctx, c_ixs, new_ctx, Abf2);

  // ---- hop 2 ----
  score_mfma_kernel<<<SGRID, 256, 0, stream>>>(Abf2, enc_ans, n_ans, NT_ans, tilemax);
  select_tiles_kernel<<<256, 256, 0, stream>>>(tilemax, NT_ans, sel_g);
  rescore_kernel<<<4096, 256, 0, stream>>>(new_ctx, enc_ans, n_ans, sel_g, sc);
  topk_kernel<<<256, 256, 0, stream>>>(sel_g, sc, (int*)d_out);
}